// Round 2
// baseline (25050.452 us; speedup 1.0000x reference)
//
#include <hip/hip_runtime.h>

#define B_  256
#define T_  512
#define F_  64
#define H_  1024
#define TL_ 64

typedef _Float16 half8 __attribute__((ext_vector_type(8)));
typedef float   floatx4 __attribute__((ext_vector_type(4)));

#define MFMA(a, b, c) __builtin_amdgcn_mfma_f32_16x16x32_f16(a, b, c, 0, 0, 0)

// ws layout (bytes)
#define WF_E   0UL          // W_hh enc fragments: 3*64*32*4*16 chunks * 16B = 6291456
#define WF_D   6291456UL    // W_hh dec fragments: 6291456
#define WF_I   12582912UL   // W_ih enc fragments: 3*64*2*4*16 * 16 = 393216
#define HP     12976128UL   // h planes: [2 pingpong][hi,lo] * 524288 = 2097152
#define PB     15073280UL   // fc partials: [2][64][256] f32 = 131072
#define BAR    15204352UL   // grid-barrier counter (4 bytes)
#define HPLANE 524288UL

// ---------------------------------------------------------------------------
// Setup: convert W_hh (enc,dec) and W_ih (enc) fp32 -> fp16 MFMA-B fragment
// layout. B-frag for 16x16x32: lane L holds B[k = (L>>4)*8 + t][n = L&15],
// i.e. W[g*H + j*16 + (L&15)][kb*32 + (L>>4)*8 + t].
// Chunk index c = (((g*64+j)*K32 + kb)*4 + q)*16 + r ; 16B per chunk.
// Also zeroes the grid-barrier counter (ws is re-poisoned before every call).
// ---------------------------------------------------------------------------
__global__ void gru_setup(const float* __restrict__ WhhE,
                          const float* __restrict__ WhhD,
                          const float* __restrict__ WihE,
                          char* __restrict__ ws) {
  int t = blockIdx.x * 256 + threadIdx.x;
  if (t == 0) *(unsigned int*)(ws + BAR) = 0u;
  const int NW = 3 * 64 * 32 * 4 * 16;  // 393216 chunks per W_hh
  if (t < 2 * NW) {
    const float* W = (t < NW) ? WhhE : WhhD;
    size_t dst = (t < NW) ? WF_E : WF_D;
    int c = (t < NW) ? t : t - NW;
    int r = c & 15, q = (c >> 4) & 3, kb = (c >> 6) & 31, gj = c >> 11;
    int row = (gj >> 6) * H_ + (gj & 63) * 16 + r;
    const float* src = W + (size_t)row * H_ + kb * 32 + q * 8;
    half8 v;
#pragma unroll
    for (int i = 0; i < 8; ++i) v[i] = (_Float16)src[i];
    *(half8*)(ws + dst + (size_t)c * 16) = v;
  } else if (t < 2 * NW + 3 * 64 * 2 * 4 * 16) {
    int c = t - 2 * NW;
    int r = c & 15, q = (c >> 4) & 3, kc = (c >> 6) & 1, gj = c >> 7;
    int row = (gj >> 6) * H_ + (gj & 63) * 16 + r;
    const float* src = WihE + (size_t)row * F_ + kc * 32 + q * 8;
    half8 v;
#pragma unroll
    for (int i = 0; i < 8; ++i) v[i] = (_Float16)src[i];
    *(half8*)(ws + WF_I + (size_t)c * 16) = v;
  }
}

// ---------------------------------------------------------------------------
// Manual grid barrier: monotone counter, device-scope atomics + fences.
// All 256 blocks are co-resident (1 block/CU via __launch_bounds__(256,1)),
// so spinning is deadlock-free without cooperative launch.
// ---------------------------------------------------------------------------
__device__ __forceinline__ void gbar(unsigned int* cnt, unsigned int target) {
  __syncthreads();
  if (threadIdx.x == 0) {
    __threadfence();  // release: make this block's h/pb stores visible
    __hip_atomic_fetch_add(cnt, 1u, __ATOMIC_RELEASE, __HIP_MEMORY_SCOPE_AGENT);
    while (__hip_atomic_load(cnt, __ATOMIC_ACQUIRE, __HIP_MEMORY_SCOPE_AGENT) <
           target)
      __builtin_amdgcn_s_sleep(1);
    __threadfence();  // acquire: invalidate CU caches before readers proceed
  }
  __syncthreads();
}

// ---------------------------------------------------------------------------
// Main persistent kernel: 512 encoder + 64 decoder steps.
// Grid 256 WGs x 256 thr. WG (m = bx&3, j = bx>>2): rows [m*64,+64),
// hidden cols [j*16,+16) (all 3 gates). Wave w owns rowblock rb = m*4+w.
// W_hh B-frags register-resident (384 VGPRs). h kept as fp16 hi/lo planes in
// fragment-major layout; A-frag = one coalesced 16B load per lane per kchunk.
// ---------------------------------------------------------------------------
__global__ __launch_bounds__(256, 1) void gru_main(
    const float* __restrict__ x,
    const float* __restrict__ bih_e, const float* __restrict__ bhh_e,
    const float* __restrict__ Wih_d,
    const float* __restrict__ bih_d, const float* __restrict__ bhh_d,
    const float* __restrict__ fcW, const float* __restrict__ fcb,
    float* __restrict__ out, char* __restrict__ ws) {

  __shared__ float inp_lds[64];
  unsigned int* bar = (unsigned int*)(ws + BAR);
  unsigned int bt = 0;

  const int tid = threadIdx.x;
  const int L = tid & 63;
  const int w = tid >> 6;
  const int bx = blockIdx.x;
  const int m = bx & 3;
  const int j = bx >> 2;
  const int r = L & 15;
  const int q = L >> 4;
  const int rb = m * 4 + w;
  const int jc = j * 16 + r;

  // zero h plane parity-0 (hi+lo = 1 MB, 65536 threads * 16B)
  {
    size_t off = ((size_t)bx * 256 + tid) * 16;
    floatx4 z = {0.f, 0.f, 0.f, 0.f};
    *(floatx4*)(ws + HP + off) = z;
  }

  float hold[4] = {0.f, 0.f, 0.f, 0.f};
  const float fcb_s = *fcb;
  const float fcw_l = fcW[jc];

  bt += 256;
  gbar(bar, bt);

  for (int phase = 0; phase < 2; ++phase) {
    // --- register-resident W_hh B-fragments: [gate][kchunk], 96 x half8 ---
    half8 bW[96];
    {
      const char* wf = ws + (phase ? WF_D : WF_E);
#pragma unroll
      for (int g = 0; g < 3; ++g)
#pragma unroll
        for (int kb = 0; kb < 32; ++kb)
          bW[g * 32 + kb] = *(const half8*)(
              wf + (size_t)((g * 64 + j) * 32 + kb) * 1024 + (size_t)L * 16);
    }
    const float* bih = phase ? bih_d : bih_e;
    const float* bhh = phase ? bhh_d : bhh_e;
    const float b_r  = bih[jc]          + bhh[jc];
    const float b_z  = bih[H_ + jc]     + bhh[H_ + jc];
    const float b_in = bih[2 * H_ + jc];
    const float b_hn = bhh[2 * H_ + jc];
    float wd_r = 0.f, wd_z = 0.f, wd_n = 0.f;
    if (phase) {
      wd_r = Wih_d[jc]; wd_z = Wih_d[H_ + jc]; wd_n = Wih_d[2 * H_ + jc];
    }

    const int nsteps = phase ? TL_ : T_;
    for (int d = 0; d < nsteps; ++d) {
      const int s = phase ? T_ + d : d;

      // ---- decoder scalar input: sum fc partials of previous step ----
      if (phase) {
        if (tid < 64) {
          float sum = fcb_s;
          if (d > 0) {
            const float* pb =
                (const float*)(ws + PB) + (size_t)((d + 1) & 1) * 64 * 256;
            int row = m * 64 + tid;
            for (int jj = 0; jj < 64; ++jj) sum += pb[jj * 256 + row];
            inp_lds[tid] = sum;
            if (j == 0) out[(size_t)row * TL_ + (d - 1)] = sum;
          } else {
            inp_lds[tid] = 0.f;
          }
        }
        __syncthreads();
      }

      floatx4 aR  = {0.f, 0.f, 0.f, 0.f}, aZ  = {0.f, 0.f, 0.f, 0.f};
      floatx4 aN  = {0.f, 0.f, 0.f, 0.f}, aI  = {0.f, 0.f, 0.f, 0.f};
      floatx4 aR2 = {0.f, 0.f, 0.f, 0.f}, aZ2 = {0.f, 0.f, 0.f, 0.f};
      floatx4 aN2 = {0.f, 0.f, 0.f, 0.f};

      // ---- h-GEMM: K=1024, 32 chunks, A hi/lo 2-term ----
      const char* hrd = ws + HP + (size_t)(s & 1) * (2 * HPLANE);
      const size_t abase = (size_t)rb * (32 * 1024) + (size_t)L * 16;
#pragma unroll
      for (int kb = 0; kb < 32; ++kb) {
        half8 ahi = *(const half8*)(hrd + abase + (size_t)kb * 1024);
        half8 alo = *(const half8*)(hrd + HPLANE + abase + (size_t)kb * 1024);
        aR  = MFMA(ahi, bW[kb],      aR);
        aZ  = MFMA(ahi, bW[32 + kb], aZ);
        aN  = MFMA(ahi, bW[64 + kb], aN);
        aR2 = MFMA(alo, bW[kb],      aR2);
        aZ2 = MFMA(alo, bW[32 + kb], aZ2);
        aN2 = MFMA(alo, bW[64 + kb], aN2);
      }

      // ---- encoder x-projection: K=64, 2 chunks ----
      if (!phase) {
        const float* xp =
            x + ((size_t)(m * 64 + w * 16 + r) * T_ + s) * F_ + q * 8;
        const char* wfi = ws + WF_I;
#pragma unroll
        for (int kc = 0; kc < 2; ++kc) {
          floatx4 x0 = *(const floatx4*)(xp + kc * 32);
          floatx4 x1 = *(const floatx4*)(xp + kc * 32 + 4);
          half8 xa;
#pragma unroll
          for (int i = 0; i < 4; ++i) {
            xa[i] = (_Float16)x0[i];
            xa[4 + i] = (_Float16)x1[i];
          }
          aR = MFMA(xa, *(const half8*)(wfi +
                   (size_t)((0 * 64 + j) * 2 + kc) * 1024 + (size_t)L * 16), aR);
          aZ = MFMA(xa, *(const half8*)(wfi +
                   (size_t)((1 * 64 + j) * 2 + kc) * 1024 + (size_t)L * 16), aZ);
          aI = MFMA(xa, *(const half8*)(wfi +
                   (size_t)((2 * 64 + j) * 2 + kc) * 1024 + (size_t)L * 16), aI);
        }
      }

      // ---- gates epilogue; write h' hi/lo in fragment layout ----
      char* hwr = ws + HP + (size_t)((s + 1) & 1) * (2 * HPLANE);
      const size_t wbase = ((size_t)rb * 32 + (size_t)(j >> 1)) * 1024 +
                           (size_t)((j & 1) * 2 + (r >> 3)) * 256 +
                           (size_t)(r & 7) * 2;
      float pv[4];
#pragma unroll
      for (int i = 0; i < 4; ++i) {
        float inp_i = phase ? inp_lds[w * 16 + q * 4 + i] : 0.f;
        float rpre = aR[i] + aR2[i] + b_r + inp_i * wd_r;
        float zpre = aZ[i] + aZ2[i] + b_z + inp_i * wd_z;
        float hn   = aN[i] + aN2[i] + b_hn;
        float inn  = aI[i] + b_in + inp_i * wd_n;
        float rg = 1.f / (1.f + __expf(-rpre));
        float zg = 1.f / (1.f + __expf(-zpre));
        float t2 = __expf(-2.f * (inn + rg * hn));
        float ng = 2.f / (1.f + t2) - 1.f;   // tanh, safe at +-inf
        float hnew = (1.f - zg) * ng + zg * hold[i];
        hold[i] = hnew;
        _Float16 hhi = (_Float16)hnew;
        float lo = hnew - (float)hhi;
        _Float16 hlo = (_Float16)lo;
        size_t wo = wbase + (size_t)(q * 4 + i) * 16;
        *(_Float16*)(hwr + wo) = hhi;
        *(_Float16*)(hwr + HPLANE + wo) = hlo;
        pv[i] = hnew * fcw_l;
      }

      // ---- decoder: fc partial dot for this j-slice ----
      if (phase) {
#pragma unroll
        for (int i = 0; i < 4; ++i) {
          float v = pv[i];
          v += __shfl_xor(v, 1);
          v += __shfl_xor(v, 2);
          v += __shfl_xor(v, 4);
          v += __shfl_xor(v, 8);
          if (r == 0) {
            float* pb = (float*)(ws + PB) + (size_t)(d & 1) * 64 * 256;
            pb[j * 256 + (m * 64 + w * 16 + q * 4 + i)] = v;
          }
        }
      }

      bt += 256;
      gbar(bar, bt);
    }
  }

  // ---- final output column t = 63 ----
  if (j == 0 && tid < 64) {
    float sum = fcb_s;
    const float* pb =
        (const float*)(ws + PB) + (size_t)((TL_ - 1) & 1) * 64 * 256;
    int row = m * 64 + tid;
    for (int jj = 0; jj < 64; ++jj) sum += pb[jj * 256 + row];
    out[(size_t)row * TL_ + (TL_ - 1)] = sum;
  }
}

// ---------------------------------------------------------------------------
extern "C" void kernel_launch(void* const* d_in, const int* in_sizes, int n_in,
                              void* d_out, int out_size, void* d_ws,
                              size_t ws_size, hipStream_t stream) {
  const float* x     = (const float*)d_in[0];
  const float* WihE  = (const float*)d_in[1];
  const float* WhhE  = (const float*)d_in[2];
  const float* bihE  = (const float*)d_in[3];
  const float* bhhE  = (const float*)d_in[4];
  const float* WihD  = (const float*)d_in[5];
  const float* WhhD  = (const float*)d_in[6];
  const float* bihD  = (const float*)d_in[7];
  const float* bhhD  = (const float*)d_in[8];
  const float* fcW   = (const float*)d_in[9];
  const float* fcb   = (const float*)d_in[10];
  float* outp = (float*)d_out;
  char* ws = (char*)d_ws;

  // fragment conversion: 811008 chunks -> 3168 blocks x 256
  gru_setup<<<3168, 256, 0, stream>>>(WhhE, WhhD, WihE, ws);

  // plain launch; co-residency is guaranteed by 1 block/CU x 256 CUs
  gru_main<<<dim3(256), dim3(256), 0, stream>>>(
      x, bihE, bhhE, WihD, bihD, bhhD, fcW, fcb, outp, ws);
}

// Round 3
// 13797.665 us; speedup vs baseline: 1.8156x; 1.8156x over previous
//
#include <hip/hip_runtime.h>

#define B_  256
#define T_  512
#define F_  64
#define H_  1024
#define TL_ 64

typedef _Float16 half8 __attribute__((ext_vector_type(8)));
typedef float   floatx4 __attribute__((ext_vector_type(4)));

#define MFMA(a, b, c) __builtin_amdgcn_mfma_f32_16x16x32_f16(a, b, c, 0, 0, 0)

// ws layout (bytes)
#define WF_E   0UL          // W_hh enc fragments: 3*64*32 chunks * 1024B = 6291456
#define WF_D   6291456UL    // W_hh dec fragments: 6291456
#define WF_I   12582912UL   // W_ih enc fragments: 3*64*2 chunks * 1024B = 393216
#define HP     12976128UL   // h planes: [2 parity][hi,lo] * 524288 = 2097152
#define PB     15073280UL   // fc partials: [2][64][256] f32 = 131072
#define BARS   15204352UL   // 8 group counters, 128B apart = 1024
#define HPLANE 524288UL

// ---------------------------------------------------------------------------
// Setup: convert W_hh (enc,dec) and W_ih (enc) fp32 -> fp16 MFMA-B fragment
// layout. B-frag for 16x16x32: lane L holds B[k=(L>>4)*8+t][n=L&15], i.e.
// W[g*H + jg*16 + (L&15)][kb*32 + (L>>4)*8 + t].
// Chunk c = (((g*64+jg)*32 + kb)*4 + q)*16 + r ; 16B per chunk-lane.
// Also zeroes the 8 group-barrier counters (ws re-poisoned every call).
// ---------------------------------------------------------------------------
__global__ void gru_setup(const float* __restrict__ WhhE,
                          const float* __restrict__ WhhD,
                          const float* __restrict__ WihE,
                          char* __restrict__ ws) {
  int t = blockIdx.x * 256 + threadIdx.x;
  if (t < 256) ((unsigned int*)(ws + BARS))[t] = 0u;
  const int NW = 3 * 64 * 32 * 4 * 16;  // 393216 chunk-lanes per W_hh
  if (t < 2 * NW) {
    const float* W = (t < NW) ? WhhE : WhhD;
    size_t dst = (t < NW) ? WF_E : WF_D;
    int c = (t < NW) ? t : t - NW;
    int r = c & 15, q = (c >> 4) & 3, kb = (c >> 6) & 31, gj = c >> 11;
    int row = (gj >> 6) * H_ + (gj & 63) * 16 + r;
    const float* src = W + (size_t)row * H_ + kb * 32 + q * 8;
    half8 v;
#pragma unroll
    for (int i = 0; i < 8; ++i) v[i] = (_Float16)src[i];
    *(half8*)(ws + dst + (size_t)c * 16) = v;
  } else if (t < 2 * NW + 3 * 64 * 2 * 4 * 16) {
    int c = t - 2 * NW;
    int r = c & 15, q = (c >> 4) & 3, kc = (c >> 6) & 1, gj = c >> 7;
    int row = (gj >> 6) * H_ + (gj & 63) * 16 + r;
    const float* src = WihE + (size_t)row * F_ + kc * 32 + q * 8;
    half8 v;
#pragma unroll
    for (int i = 0; i < 8; ++i) v[i] = (_Float16)src[i];
    *(half8*)(ws + WF_I + (size_t)c * 16) = v;
  }
}

// ---------------------------------------------------------------------------
// Group barrier: 32 blocks per group (same mtb), own cacheline counter.
// ---------------------------------------------------------------------------
__device__ __forceinline__ void gbar(unsigned int* cnt, unsigned int target) {
  __syncthreads();
  if (threadIdx.x == 0) {
    __threadfence();  // release: h'/pb stores -> LLC
    __hip_atomic_fetch_add(cnt, 1u, __ATOMIC_RELEASE, __HIP_MEMORY_SCOPE_AGENT);
    while (__hip_atomic_load(cnt, __ATOMIC_ACQUIRE, __HIP_MEMORY_SCOPE_AGENT) <
           target)
      __builtin_amdgcn_s_sleep(1);
    __threadfence();  // acquire
  }
  __syncthreads();
}

// ---------------------------------------------------------------------------
// Main persistent kernel, 256 WGs x 256 thr (1 block/CU).
// Block (mtb = bx&7, jgp = bx>>3): rows [mtb*32,+32), cols [jgp*32,+32).
// Wave w: jg = jgp*2 + (w&1), K-half kh = w>>1. Each wave owns B-frags for
// (16 cols x 3 gates x K=512) = 48 chunks = 192 VGPRs -> NO SPILL (vs 384
// last round, which spilled at the 256-VGPR allocation and cost 10x).
// kh0+kh1 partials reduced via LDS; kh0 does the gate epilogue.
// Sync: per-mtb-group 32-block barrier (recurrence is row-block-local).
// ---------------------------------------------------------------------------
__global__ __launch_bounds__(256, 1) void gru_main(
    const float* __restrict__ x,
    const float* __restrict__ bih_e, const float* __restrict__ bhh_e,
    const float* __restrict__ Wih_d,
    const float* __restrict__ bih_d, const float* __restrict__ bhh_d,
    const float* __restrict__ fcW, const float* __restrict__ fcb,
    float* __restrict__ out, char* __restrict__ ws) {

  __shared__ float inp_lds[32];
  __shared__ float red[2 * 64 * 33];  // [pair][lane][32 vals + pad]

  const int tid = threadIdx.x;
  const int L = tid & 63;
  const int w = tid >> 6;
  const int bx = blockIdx.x;
  const int mtb = bx & 7;
  const int jgp = bx >> 3;
  const int jgl = w & 1;
  const int kh = w >> 1;
  const int jg = jgp * 2 + jgl;
  const int r = L & 15;
  const int q = L >> 4;
  const int jc = jg * 16 + r;

  unsigned int* bar = (unsigned int*)(ws + BARS) + (size_t)mtb * 32;
  unsigned int bt = 0;

  // zero this group's slice of h plane parity-0 (hi+lo)
  {
    char* base = ws + HP + ((tid < 128) ? 0UL : HPLANE) +
                 (size_t)mtb * 65536 + (size_t)jgp * 2048;
    floatx4 z = {0.f, 0.f, 0.f, 0.f};
    *(floatx4*)(base + (size_t)(tid & 127) * 16) = z;
  }

  float hold[8] = {0.f, 0.f, 0.f, 0.f, 0.f, 0.f, 0.f, 0.f};
  const float fcb_s = *fcb;
  const float fcw_l = fcW[jc];

  bt += 32;
  gbar(bar, bt);

  for (int phase = 0; phase < 2; ++phase) {
    // register-resident B fragments: [gate][kk] for this wave's K-half
    half8 bW[48];
    {
      const char* wf = ws + (phase ? WF_D : WF_E);
#pragma unroll
      for (int g = 0; g < 3; ++g)
#pragma unroll
        for (int kk = 0; kk < 16; ++kk)
          bW[g * 16 + kk] = *(const half8*)(
              wf + (size_t)((g * 64 + jg) * 32 + kh * 16 + kk) * 1024 +
              (size_t)L * 16);
    }
    half8 bWI[6];
    if (!phase) {
#pragma unroll
      for (int g = 0; g < 3; ++g)
#pragma unroll
        for (int kc = 0; kc < 2; ++kc)
          bWI[g * 2 + kc] = *(const half8*)(
              ws + WF_I + (size_t)((g * 64 + jg) * 2 + kc) * 1024 +
              (size_t)L * 16);
    }
    const float* bih = phase ? bih_d : bih_e;
    const float* bhh = phase ? bhh_d : bhh_e;
    const float b_r  = bih[jc]          + bhh[jc];
    const float b_z  = bih[H_ + jc]     + bhh[H_ + jc];
    const float b_in = bih[2 * H_ + jc];
    const float b_hn = bhh[2 * H_ + jc];
    float wd_r = 0.f, wd_z = 0.f, wd_n = 0.f;
    if (phase) {
      wd_r = Wih_d[jc]; wd_z = Wih_d[H_ + jc]; wd_n = Wih_d[2 * H_ + jc];
    }

    const int nsteps = phase ? TL_ : T_;
    for (int d = 0; d < nsteps; ++d) {
      const int s = phase ? T_ + d : d;

      // ---- decoder scalar input from previous step's fc partials ----
      if (phase && tid < 32) {
        float sum = 0.f;
        if (d > 0) {
          const float* pb =
              (const float*)(ws + PB) + (size_t)((d + 1) & 1) * 64 * 256;
          int row = mtb * 32 + tid;
          float a = fcb_s;
          for (int jj = 0; jj < 64; ++jj) a += pb[jj * 256 + row];
          sum = a;
          if (jgp == 0) out[(size_t)row * TL_ + (d - 1)] = a;
        }
        inp_lds[tid] = sum;
      }

      floatx4 acc[2][3];
      floatx4 aI[2];
#pragma unroll
      for (int t = 0; t < 2; ++t) {
#pragma unroll
        for (int g = 0; g < 3; ++g) acc[t][g] = (floatx4){0.f, 0.f, 0.f, 0.f};
        aI[t] = (floatx4){0.f, 0.f, 0.f, 0.f};
      }

      // ---- h-GEMM, this wave's K-half; hi+lo planes into same fp32 acc ----
      const char* hrd = ws + HP + (size_t)(s & 1) * (2 * HPLANE);
#pragma unroll
      for (int kk = 0; kk < 16; ++kk) {
        const int kb = kh * 16 + kk;
#pragma unroll
        for (int t = 0; t < 2; ++t) {
          const char* ab = hrd + (size_t)(mtb * 2 + t) * 32768 +
                           (size_t)kb * 1024 + (size_t)L * 16;
          half8 ahi = *(const half8*)ab;
          half8 alo = *(const half8*)(ab + HPLANE);
#pragma unroll
          for (int g = 0; g < 3; ++g) {
            acc[t][g] = MFMA(ahi, bW[g * 16 + kk], acc[t][g]);
            acc[t][g] = MFMA(alo, bW[g * 16 + kk], acc[t][g]);
          }
        }
      }

      // ---- kh1: encoder x-projection + dump partials to LDS ----
      if (kh == 1) {
        if (!phase) {
#pragma unroll
          for (int t = 0; t < 2; ++t) {
            const float* xp =
                x + ((size_t)(mtb * 32 + t * 16 + r) * T_ + s) * F_ + q * 8;
#pragma unroll
            for (int kc = 0; kc < 2; ++kc) {
              floatx4 x0 = *(const floatx4*)(xp + kc * 32);
              floatx4 x1 = *(const floatx4*)(xp + kc * 32 + 4);
              half8 xa;
#pragma unroll
              for (int i = 0; i < 4; ++i) {
                xa[i] = (_Float16)x0[i];
                xa[4 + i] = (_Float16)x1[i];
              }
              acc[t][0] = MFMA(xa, bWI[0 * 2 + kc], acc[t][0]);
              acc[t][1] = MFMA(xa, bWI[1 * 2 + kc], acc[t][1]);
              aI[t]     = MFMA(xa, bWI[2 * 2 + kc], aI[t]);
            }
          }
        }
        float* rd = &red[(jgl * 64 + L) * 33];
#pragma unroll
        for (int t = 0; t < 2; ++t)
#pragma unroll
          for (int g = 0; g < 3; ++g)
#pragma unroll
            for (int i = 0; i < 4; ++i) rd[(t * 3 + g) * 4 + i] = acc[t][g][i];
        if (!phase) {
#pragma unroll
          for (int t = 0; t < 2; ++t)
#pragma unroll
            for (int i = 0; i < 4; ++i) rd[24 + t * 4 + i] = aI[t][i];
        }
      }
      __syncthreads();

      // ---- kh0: reduce K-halves, gate epilogue, write h' hi/lo ----
      if (kh == 0) {
        const float* rd = &red[(jgl * 64 + L) * 33];
        char* hwr = ws + HP + (size_t)((s + 1) & 1) * (2 * HPLANE);
#pragma unroll
        for (int t = 0; t < 2; ++t) {
          const size_t wbase = (size_t)(mtb * 2 + t) * 32768 +
                               (size_t)(jg >> 1) * 1024 +
                               (size_t)((jg & 1) * 2 + (r >> 3)) * 256 +
                               (size_t)(r & 7) * 2;
          float pv[4];
#pragma unroll
          for (int i = 0; i < 4; ++i) {
            float rpre = acc[t][0][i] + rd[(t * 3 + 0) * 4 + i] + b_r;
            float zpre = acc[t][1][i] + rd[(t * 3 + 1) * 4 + i] + b_z;
            float hn   = acc[t][2][i] + rd[(t * 3 + 2) * 4 + i] + b_hn;
            float inn  = b_in + (phase ? 0.f : rd[24 + t * 4 + i]);
            if (phase) {
              float inp = inp_lds[t * 16 + q * 4 + i];
              rpre += inp * wd_r;
              zpre += inp * wd_z;
              inn  += inp * wd_n;
            }
            float rg = 1.f / (1.f + __expf(-rpre));
            float zg = 1.f / (1.f + __expf(-zpre));
            float t2 = __expf(-2.f * (inn + rg * hn));
            float ng = 2.f / (1.f + t2) - 1.f;  // tanh, safe at +-inf
            float hnew = (1.f - zg) * ng + zg * hold[t * 4 + i];
            hold[t * 4 + i] = hnew;
            _Float16 hhi = (_Float16)hnew;
            float lo = hnew - (float)hhi;
            _Float16 hlo = (_Float16)lo;
            size_t wo = wbase + (size_t)(q * 4 + i) * 16;
            *(_Float16*)(hwr + wo) = hhi;
            *(_Float16*)(hwr + HPLANE + wo) = hlo;
            pv[i] = hnew * fcw_l;
          }
          if (phase) {
#pragma unroll
            for (int i = 0; i < 4; ++i) {
              float v = pv[i];
              v += __shfl_xor(v, 1);
              v += __shfl_xor(v, 2);
              v += __shfl_xor(v, 4);
              v += __shfl_xor(v, 8);
              if (r == 0) {
                float* pb = (float*)(ws + PB) + (size_t)(d & 1) * 64 * 256;
                pb[jg * 256 + (mtb * 32 + t * 16 + q * 4 + i)] = v;
              }
            }
          }
        }
      }

      bt += 32;
      gbar(bar, bt);
    }
  }

  // ---- final output column t = TL-1 ----
  if (jgp == 0 && tid < 32) {
    const float* pb =
        (const float*)(ws + PB) + (size_t)((TL_ - 1) & 1) * 64 * 256;
    int row = mtb * 32 + tid;
    float a = fcb_s;
    for (int jj = 0; jj < 64; ++jj) a += pb[jj * 256 + row];
    out[(size_t)row * TL_ + (TL_ - 1)] = a;
  }
}

// ---------------------------------------------------------------------------
extern "C" void kernel_launch(void* const* d_in, const int* in_sizes, int n_in,
                              void* d_out, int out_size, void* d_ws,
                              size_t ws_size, hipStream_t stream) {
  const float* x     = (const float*)d_in[0];
  const float* WihE  = (const float*)d_in[1];
  const float* WhhE  = (const float*)d_in[2];
  const float* bihE  = (const float*)d_in[3];
  const float* bhhE  = (const float*)d_in[4];
  const float* WihD  = (const float*)d_in[5];
  const float* WhhD  = (const float*)d_in[6];
  const float* bihD  = (const float*)d_in[7];
  const float* bhhD  = (const float*)d_in[8];
  const float* fcW   = (const float*)d_in[9];
  const float* fcb   = (const float*)d_in[10];
  float* outp = (float*)d_out;
  char* ws = (char*)d_ws;

  gru_setup<<<3168, 256, 0, stream>>>(WhhE, WhhD, WihE, ws);

  gru_main<<<dim3(256), dim3(256), 0, stream>>>(
      x, bihE, bhhE, WihD, bihD, bhhD, fcW, fcb, outp, ws);
}

// Round 4
// 10552.623 us; speedup vs baseline: 2.3739x; 1.3075x over previous
//
#include <hip/hip_runtime.h>

#define B_  256
#define T_  512
#define F_  64
#define H_  1024
#define TL_ 64

typedef _Float16 half8 __attribute__((ext_vector_type(8)));
typedef float   floatx4 __attribute__((ext_vector_type(4)));
typedef unsigned long long ull;

#define MFMA(a, b, c) __builtin_amdgcn_mfma_f32_16x16x32_f16(a, b, c, 0, 0, 0)

// ws layout (bytes)
#define WF_E   0UL          // W_hh enc fragments: 3*64*32 chunks * 1024B = 6291456
#define WF_D   6291456UL    // W_hh dec fragments: 6291456
#define WF_I   12582912UL   // W_ih enc fragments: 3*64*2 chunks * 1024B = 393216
#define HP     12976128UL   // h planes: [2 parity][hi,lo] * 524288 = 2097152
#define PB     15073280UL   // fc partials: [2][64][256] f32 = 131072
#define BARS   15204352UL   // 8 group counters, 128B apart
#define HPLANE 524288UL

// All cross-block data (h planes, pb, barrier) moves via relaxed AGENT-scope
// atomics -> sc0|sc1 accesses, coherent at the Infinity Cache. NO
// __threadfence / buffer_wbl2 / buffer_inv anywhere in the hot loop (round-3
// profile: those cache-maintenance ops cost ~20us/step, WRITE_SIZE=654MB).
__device__ __forceinline__ ull lda8(const void* p) {
  return __hip_atomic_load((const ull*)p, __ATOMIC_RELAXED,
                           __HIP_MEMORY_SCOPE_AGENT);
}
__device__ __forceinline__ void sta8(void* p, ull v) {
  __hip_atomic_store((ull*)p, v, __ATOMIC_RELAXED, __HIP_MEMORY_SCOPE_AGENT);
}
union H8 { ull u[2]; half8 v; };
__device__ __forceinline__ half8 ldA(const char* p) {
  H8 x;
  x.u[0] = lda8(p);
  x.u[1] = lda8(p + 8);
  return x.v;
}

// ---------------------------------------------------------------------------
// Setup: convert W_hh (enc,dec) and W_ih (enc) fp32 -> fp16 MFMA-B fragment
// layout. B-frag for 16x16x32: lane L holds B[k=(L>>4)*8+t][n=L&15], i.e.
// W[g*H + jg*16 + (L&15)][kb*32 + (L>>4)*8 + t].
// Chunk c = (((g*64+jg)*32 + kb)*4 + q)*16 + r ; 16B per chunk-lane.
// Also zeroes the group-barrier counters (ws re-poisoned every call).
// ---------------------------------------------------------------------------
__global__ void gru_setup(const float* __restrict__ WhhE,
                          const float* __restrict__ WhhD,
                          const float* __restrict__ WihE,
                          char* __restrict__ ws) {
  int t = blockIdx.x * 256 + threadIdx.x;
  if (t < 256) ((unsigned int*)(ws + BARS))[t] = 0u;
  const int NW = 3 * 64 * 32 * 4 * 16;  // 393216 chunk-lanes per W_hh
  if (t < 2 * NW) {
    const float* W = (t < NW) ? WhhE : WhhD;
    size_t dst = (t < NW) ? WF_E : WF_D;
    int c = (t < NW) ? t : t - NW;
    int r = c & 15, q = (c >> 4) & 3, kb = (c >> 6) & 31, gj = c >> 11;
    int row = (gj >> 6) * H_ + (gj & 63) * 16 + r;
    const float* src = W + (size_t)row * H_ + kb * 32 + q * 8;
    half8 v;
#pragma unroll
    for (int i = 0; i < 8; ++i) v[i] = (_Float16)src[i];
    *(half8*)(ws + dst + (size_t)c * 16) = v;
  } else if (t < 2 * NW + 3 * 64 * 2 * 4 * 16) {
    int c = t - 2 * NW;
    int r = c & 15, q = (c >> 4) & 3, kc = (c >> 6) & 1, gj = c >> 7;
    int row = (gj >> 6) * H_ + (gj & 63) * 16 + r;
    const float* src = WihE + (size_t)row * F_ + kc * 32 + q * 8;
    half8 v;
#pragma unroll
    for (int i = 0; i < 8; ++i) v[i] = (_Float16)src[i];
    *(half8*)(ws + WF_I + (size_t)c * 16) = v;
  }
}

// ---------------------------------------------------------------------------
// Group barrier: 32 blocks (same mtb), own cacheline. Relaxed atomics only:
// the __syncthreads() before the add drains every thread's outstanding
// atomic stores (compiler emits per-thread s_waitcnt vmcnt(0)), and the LLC
// is the coherence point, so no release/acquire cache ops are needed.
// ---------------------------------------------------------------------------
__device__ __forceinline__ void gbar(unsigned int* cnt, unsigned int target) {
  __syncthreads();
  if (threadIdx.x == 0) {
    __hip_atomic_fetch_add(cnt, 1u, __ATOMIC_RELAXED,
                           __HIP_MEMORY_SCOPE_AGENT);
    while (__hip_atomic_load(cnt, __ATOMIC_RELAXED,
                             __HIP_MEMORY_SCOPE_AGENT) < target)
      __builtin_amdgcn_s_sleep(1);
  }
  __syncthreads();
}

// ---------------------------------------------------------------------------
// Main persistent kernel, 256 WGs x 256 thr (1 block/CU).
// Block (mtb = bx&7, jgp = bx>>3): rows [mtb*32,+32), cols [jgp*32,+32).
// Wave w: jg = jgp*2 + (w&1), K-half kh = w>>1; 48 B-frag chunks = 192 VGPR
// per wave (no spill). kh partials reduced via LDS; kh0 does the epilogue.
// h' routed through a 4KB LDS tile (exact image of the block's contiguous
// global region) then streamed out as coalesced 8B LLC atomics.
// ---------------------------------------------------------------------------
__global__ __launch_bounds__(256, 1) void gru_main(
    const float* __restrict__ x,
    const float* __restrict__ bih_e, const float* __restrict__ bhh_e,
    const float* __restrict__ Wih_d,
    const float* __restrict__ bih_d, const float* __restrict__ bhh_d,
    const float* __restrict__ fcW, const float* __restrict__ fcb,
    float* __restrict__ out, char* __restrict__ ws) {

  __shared__ float inp_lds[32];
  __shared__ float red[2 * 64 * 33];          // kh-half partial exchange
  __shared__ __align__(16) char tile[4096];   // h' image: [hi|lo][t][L][16B]

  const int tid = threadIdx.x;
  const int L = tid & 63;
  const int w = tid >> 6;
  const int bx = blockIdx.x;
  const int mtb = bx & 7;
  const int jgp = bx >> 3;
  const int jgl = w & 1;
  const int kh = w >> 1;
  const int jg = jgp * 2 + jgl;
  const int r = L & 15;
  const int q = L >> 4;
  const int jc = jg * 16 + r;

  unsigned int* bar = (unsigned int*)(ws + BARS) + (size_t)mtb * 32;
  unsigned int bt = 0;

  // stream-out / init indexing: thread u -> (plane, t, Lseg)
  const int so_plane = tid >> 7;
  const int so_t = (tid >> 6) & 1;
  const int so_L = tid & 63;
  const size_t so_off = (size_t)(mtb * 2 + so_t) * 32768 +
                        (size_t)jgp * 1024 + (size_t)so_L * 16;

  // zero this block's own write-region of h parity-0 (hi+lo), LLC-coherent
  {
    char* dst = ws + HP + (size_t)so_plane * HPLANE + so_off;
    sta8(dst, 0ull);
    sta8(dst + 8, 0ull);
  }

  float hold[8] = {0.f, 0.f, 0.f, 0.f, 0.f, 0.f, 0.f, 0.f};
  const float fcb_s = *fcb;
  const float fcw_l = fcW[jc];

  bt += 32;
  gbar(bar, bt);

  for (int phase = 0; phase < 2; ++phase) {
    // register-resident B fragments: [gate][kk] for this wave's K-half
    half8 bW[48];
    {
      const char* wf = ws + (phase ? WF_D : WF_E);
#pragma unroll
      for (int g = 0; g < 3; ++g)
#pragma unroll
        for (int kk = 0; kk < 16; ++kk)
          bW[g * 16 + kk] = *(const half8*)(
              wf + (size_t)((g * 64 + jg) * 32 + kh * 16 + kk) * 1024 +
              (size_t)L * 16);
    }
    half8 bWI[6];
    if (!phase) {
#pragma unroll
      for (int g = 0; g < 3; ++g)
#pragma unroll
        for (int kc = 0; kc < 2; ++kc)
          bWI[g * 2 + kc] = *(const half8*)(
              ws + WF_I + (size_t)((g * 64 + jg) * 2 + kc) * 1024 +
              (size_t)L * 16);
    }
    const float* bih = phase ? bih_d : bih_e;
    const float* bhh = phase ? bhh_d : bhh_e;
    const float b_r  = bih[jc]          + bhh[jc];
    const float b_z  = bih[H_ + jc]     + bhh[H_ + jc];
    const float b_in = bih[2 * H_ + jc];
    const float b_hn = bhh[2 * H_ + jc];
    float wd_r = 0.f, wd_z = 0.f, wd_n = 0.f;
    if (phase) {
      wd_r = Wih_d[jc]; wd_z = Wih_d[H_ + jc]; wd_n = Wih_d[2 * H_ + jc];
    }

    const int nsteps = phase ? TL_ : T_;
    for (int d = 0; d < nsteps; ++d) {
      const int s = phase ? T_ + d : d;

      // ---- decoder scalar input from previous step's fc partials ----
      if (phase && tid < 32) {
        float sum = 0.f;
        if (d > 0) {
          const float* pb =
              (const float*)(ws + PB) + (size_t)((d + 1) & 1) * 64 * 256;
          int row = mtb * 32 + tid;
          float a = fcb_s;
          for (int jj = 0; jj < 64; ++jj)
            a += __hip_atomic_load(&pb[jj * 256 + row], __ATOMIC_RELAXED,
                                   __HIP_MEMORY_SCOPE_AGENT);
          sum = a;
          if (jgp == 0) out[(size_t)row * TL_ + (d - 1)] = a;
        }
        inp_lds[tid] = sum;
      }

      floatx4 acc[2][3];
      floatx4 aI[2];
#pragma unroll
      for (int t = 0; t < 2; ++t) {
#pragma unroll
        for (int g = 0; g < 3; ++g) acc[t][g] = (floatx4){0.f, 0.f, 0.f, 0.f};
        aI[t] = (floatx4){0.f, 0.f, 0.f, 0.f};
      }

      // ---- h-GEMM, this wave's K-half; hi+lo planes, LLC atomic loads ----
      const char* hrd = ws + HP + (size_t)(s & 1) * (2 * HPLANE);
#pragma unroll
      for (int kk = 0; kk < 16; ++kk) {
        const int kb = kh * 16 + kk;
#pragma unroll
        for (int t = 0; t < 2; ++t) {
          const char* ab = hrd + (size_t)(mtb * 2 + t) * 32768 +
                           (size_t)kb * 1024 + (size_t)L * 16;
          half8 ahi = ldA(ab);
          half8 alo = ldA(ab + HPLANE);
#pragma unroll
          for (int g = 0; g < 3; ++g) {
            acc[t][g] = MFMA(ahi, bW[g * 16 + kk], acc[t][g]);
            acc[t][g] = MFMA(alo, bW[g * 16 + kk], acc[t][g]);
          }
        }
      }

      // ---- kh1: encoder x-projection + dump partials to LDS ----
      if (kh == 1) {
        if (!phase) {
#pragma unroll
          for (int t = 0; t < 2; ++t) {
            const float* xp =
                x + ((size_t)(mtb * 32 + t * 16 + r) * T_ + s) * F_ + q * 8;
#pragma unroll
            for (int kc = 0; kc < 2; ++kc) {
              floatx4 x0 = *(const floatx4*)(xp + kc * 32);
              floatx4 x1 = *(const floatx4*)(xp + kc * 32 + 4);
              half8 xa;
#pragma unroll
              for (int i = 0; i < 4; ++i) {
                xa[i] = (_Float16)x0[i];
                xa[4 + i] = (_Float16)x1[i];
              }
              acc[t][0] = MFMA(xa, bWI[0 * 2 + kc], acc[t][0]);
              acc[t][1] = MFMA(xa, bWI[1 * 2 + kc], acc[t][1]);
              aI[t]     = MFMA(xa, bWI[2 * 2 + kc], aI[t]);
            }
          }
        }
        float* rd = &red[(jgl * 64 + L) * 33];
#pragma unroll
        for (int t = 0; t < 2; ++t)
#pragma unroll
          for (int g = 0; g < 3; ++g)
#pragma unroll
            for (int i = 0; i < 4; ++i) rd[(t * 3 + g) * 4 + i] = acc[t][g][i];
        if (!phase) {
#pragma unroll
          for (int t = 0; t < 2; ++t)
#pragma unroll
            for (int i = 0; i < 4; ++i) rd[24 + t * 4 + i] = aI[t][i];
        }
      }
      __syncthreads();

      // ---- kh0: reduce K-halves, gate epilogue, h' -> LDS tile ----
      if (kh == 0) {
        const float* rd = &red[(jgl * 64 + L) * 33];
#pragma unroll
        for (int t = 0; t < 2; ++t) {
          const size_t tbase = (size_t)t * 1024 +
                               (size_t)(jgl * 2 + (r >> 3)) * 256 +
                               (size_t)(r & 7) * 2;
          float pv[4];
#pragma unroll
          for (int i = 0; i < 4; ++i) {
            float rpre = acc[t][0][i] + rd[(t * 3 + 0) * 4 + i] + b_r;
            float zpre = acc[t][1][i] + rd[(t * 3 + 1) * 4 + i] + b_z;
            float hn   = acc[t][2][i] + rd[(t * 3 + 2) * 4 + i] + b_hn;
            float inn  = b_in + (phase ? 0.f : rd[24 + t * 4 + i]);
            if (phase) {
              float inp = inp_lds[t * 16 + q * 4 + i];
              rpre += inp * wd_r;
              zpre += inp * wd_z;
              inn  += inp * wd_n;
            }
            float rg = 1.f / (1.f + __expf(-rpre));
            float zg = 1.f / (1.f + __expf(-zpre));
            float t2 = __expf(-2.f * (inn + rg * hn));
            float ng = 2.f / (1.f + t2) - 1.f;  // tanh, safe at +-inf
            float hnew = (1.f - zg) * ng + zg * hold[t * 4 + i];
            hold[t * 4 + i] = hnew;
            _Float16 hhi = (_Float16)hnew;
            float lo = hnew - (float)hhi;
            _Float16 hlo = (_Float16)lo;
            size_t to = tbase + (size_t)(q * 4 + i) * 16;
            *(_Float16*)(tile + to) = hhi;
            *(_Float16*)(tile + 2048 + to) = hlo;
            pv[i] = hnew * fcw_l;
          }
          if (phase) {
#pragma unroll
            for (int i = 0; i < 4; ++i) {
              float v = pv[i];
              v += __shfl_xor(v, 1);
              v += __shfl_xor(v, 2);
              v += __shfl_xor(v, 4);
              v += __shfl_xor(v, 8);
              if (r == 0) {
                float* pb = (float*)(ws + PB) + (size_t)(d & 1) * 64 * 256;
                __hip_atomic_store(
                    &pb[jg * 256 + (mtb * 32 + t * 16 + q * 4 + i)], v,
                    __ATOMIC_RELAXED, __HIP_MEMORY_SCOPE_AGENT);
              }
            }
          }
        }
      }
      __syncthreads();

      // ---- stream h' tile out: coalesced 8B LLC atomic stores ----
      {
        const char* srcp = tile + (size_t)so_plane * 2048 +
                           (size_t)so_t * 1024 + (size_t)so_L * 16;
        ull v0 = *(const ull*)srcp;
        ull v1 = *(const ull*)(srcp + 8);
        char* dst = ws + HP + (size_t)((s + 1) & 1) * (2 * HPLANE) +
                    (size_t)so_plane * HPLANE + so_off;
        sta8(dst, v0);
        sta8(dst + 8, v1);
      }

      bt += 32;
      gbar(bar, bt);
    }
  }

  // ---- final output column t = TL-1 ----
  if (jgp == 0 && tid < 32) {
    const float* pb =
        (const float*)(ws + PB) + (size_t)((TL_ - 1) & 1) * 64 * 256;
    int row = mtb * 32 + tid;
    float a = fcb_s;
    for (int jj = 0; jj < 64; ++jj)
      a += __hip_atomic_load(&pb[jj * 256 + row], __ATOMIC_RELAXED,
                             __HIP_MEMORY_SCOPE_AGENT);
    out[(size_t)row * TL_ + (TL_ - 1)] = a;
  }
}

// ---------------------------------------------------------------------------
extern "C" void kernel_launch(void* const* d_in, const int* in_sizes, int n_in,
                              void* d_out, int out_size, void* d_ws,
                              size_t ws_size, hipStream_t stream) {
  const float* x     = (const float*)d_in[0];
  const float* WihE  = (const float*)d_in[1];
  const float* WhhE  = (const float*)d_in[2];
  const float* bihE  = (const float*)d_in[3];
  const float* bhhE  = (const float*)d_in[4];
  const float* WihD  = (const float*)d_in[5];
  const float* WhhD  = (const float*)d_in[6];
  const float* bihD  = (const float*)d_in[7];
  const float* bhhD  = (const float*)d_in[8];
  const float* fcW   = (const float*)d_in[9];
  const float* fcb   = (const float*)d_in[10];
  float* outp = (float*)d_out;
  char* ws = (char*)d_ws;

  gru_setup<<<3168, 256, 0, stream>>>(WhhE, WhhD, WihE, ws);

  gru_main<<<dim3(256), dim3(256), 0, stream>>>(
      x, bihE, bhhE, WihD, bihD, bhhD, fcW, fcb, outp, ws);
}

// Round 5
// 5234.372 us; speedup vs baseline: 4.7858x; 2.0160x over previous
//
#include <hip/hip_runtime.h>

#define B_  256
#define T_  512
#define F_  64
#define H_  1024
#define TL_ 64

typedef _Float16 half8 __attribute__((ext_vector_type(8)));
typedef float   floatx4 __attribute__((ext_vector_type(4)));
typedef unsigned long long ull;

#define MFMA(a, b, c) __builtin_amdgcn_mfma_f32_16x16x32_f16(a, b, c, 0, 0, 0)

// ws layout (bytes)
#define WF_E   0UL          // W_hh enc fragments: 3*64*32 chunks * 1024B
#define WF_D   6291456UL    // W_hh dec fragments
#define WF_I   12582912UL   // W_ih enc fragments: 3*64*2 chunks * 1024B
#define HP     12976128UL   // h planes: [2 parity][hi,lo]; plane = 512KB
#define PB     15073280UL   // fc partials: [2][64 jg][256 rows] f32
#define BARS   15204352UL   // 16 group counters, 128B apart
#define HPLANE 524288UL
// h plane layout (fragment-major): [rg 16][kb 32][lane 64][16B]; the slab for
// row-group rg is 32KB/plane; block (rg,cb) owns the contiguous 2KB at
// rg*32768 + cb*2048 (cols cb*64..+64 == kb pair cb*2..cb*2+1).

// LLC-coherent scalar atomics (sc0 sc1: bypass L1/L2, coherent at IF).
__device__ __forceinline__ void sta8(void* p, ull v) {
  __hip_atomic_store((ull*)p, v, __ATOMIC_RELAXED, __HIP_MEMORY_SCOPE_AGENT);
}
__device__ __forceinline__ float lda4f(const float* p) {
  return __hip_atomic_load(p, __ATOMIC_RELAXED, __HIP_MEMORY_SCOPE_AGENT);
}

// ---------------------------------------------------------------------------
// Setup: W_hh (enc,dec) and W_ih (enc) fp32 -> fp16 MFMA-B fragment layout.
// B-frag 16x16x32: lane L holds B[k=(L>>4)*8+t][n=L&15] ->
// W[g*H + jg*16 + (L&15)][kb*32 + (L>>4)*8 + t].
// Chunk c = (((g*64+jg)*32 + kb)*4 + q)*16 + r ; 16B per chunk-lane.
// ---------------------------------------------------------------------------
__global__ void gru_setup(const float* __restrict__ WhhE,
                          const float* __restrict__ WhhD,
                          const float* __restrict__ WihE,
                          char* __restrict__ ws) {
  int t = blockIdx.x * 256 + threadIdx.x;
  if (t < 512) ((unsigned int*)(ws + BARS))[t] = 0u;
  const int NW = 3 * 64 * 32 * 4 * 16;
  if (t < 2 * NW) {
    const float* W = (t < NW) ? WhhE : WhhD;
    size_t dst = (t < NW) ? WF_E : WF_D;
    int c = (t < NW) ? t : t - NW;
    int r = c & 15, q = (c >> 4) & 3, kb = (c >> 6) & 31, gj = c >> 11;
    int row = (gj >> 6) * H_ + (gj & 63) * 16 + r;
    const float* src = W + (size_t)row * H_ + kb * 32 + q * 8;
    half8 v;
#pragma unroll
    for (int i = 0; i < 8; ++i) v[i] = (_Float16)src[i];
    *(half8*)(ws + dst + (size_t)c * 16) = v;
  } else if (t < 2 * NW + 3 * 64 * 2 * 4 * 16) {
    int c = t - 2 * NW;
    int r = c & 15, q = (c >> 4) & 3, kc = (c >> 6) & 1, gj = c >> 7;
    int row = (gj >> 6) * H_ + (gj & 63) * 16 + r;
    const float* src = WihE + (size_t)row * F_ + kc * 32 + q * 8;
    half8 v;
#pragma unroll
    for (int i = 0; i < 8; ++i) v[i] = (_Float16)src[i];
    *(half8*)(ws + WF_I + (size_t)c * 16) = v;
  }
}

// Group barrier: 16 blocks (same rg), own cacheline, relaxed LLC atomics.
__device__ __forceinline__ void gbar(unsigned int* cnt, unsigned int target) {
  __syncthreads();
  if (threadIdx.x == 0) {
    __hip_atomic_fetch_add(cnt, 1u, __ATOMIC_RELAXED,
                           __HIP_MEMORY_SCOPE_AGENT);
    while (__hip_atomic_load(cnt, __ATOMIC_RELAXED,
                             __HIP_MEMORY_SCOPE_AGENT) < target)
      __builtin_amdgcn_s_sleep(1);
  }
  __syncthreads();
}

// ---------------------------------------------------------------------------
// Main persistent kernel: 256 blocks x 512 thr (8 waves, 1 block/CU).
// Block (rg = bx&15, cb = bx>>4): rows [rg*16,+16), h-cols [cb*64,+64).
// Wave w: jp = w&3 (jg = cb*4+jp), kh = w>>2 (K-half). B-frags: 3 gates x
// 16 kb = 48 chunks = 192 VGPR/wave (cap 256 at 2 waves/SIMD).
// A slab (32KB/plane) staged to LDS once per block via 16B sc0sc1 loads
// (round-4 was fabric-BW-bound at 64MB/step issued; this is 16MB/step).
// kh halves exchange partials via LDS; kh0 does the gate epilogue.
// ---------------------------------------------------------------------------
__global__ __launch_bounds__(512, 2) void gru_main(
    const float* __restrict__ x,
    const float* __restrict__ bih_e, const float* __restrict__ bhh_e,
    const float* __restrict__ Wih_d,
    const float* __restrict__ bih_d, const float* __restrict__ bhh_d,
    const float* __restrict__ fcW, const float* __restrict__ fcb,
    float* __restrict__ out, char* __restrict__ ws) {

  __shared__ __align__(128) char atile[65536];  // [plane 2][kb 32][L 64][16B], xor-swizzled
  __shared__ float red[4 * 64 * 17];            // kh1 partials [jp][L][17]
  __shared__ __align__(16) char otile[4096];    // h' image [plane 2][2KB]
  __shared__ float inp_lds[16];

  const int tid = threadIdx.x;
  const int L = tid & 63;
  const int w = tid >> 6;
  const int jp = w & 3;
  const int kh = w >> 2;
  const int bx = blockIdx.x;
  const int rg = bx & 15;
  const int cb = bx >> 4;
  const int r = L & 15;
  const int q = L >> 4;
  const int jg = cb * 4 + jp;
  const int jc = jg * 16 + r;
  // lane's swizzled in-plane fragment offset: bits4-6 ^= (L>>3)&7
  const int lswz = (L * 16) ^ (((L >> 3) & 7) << 4);

  unsigned int* bar = (unsigned int*)(ws + BARS) + (size_t)rg * 32;
  unsigned int bt = 0;

  // staging / stream-out mapping: thread -> (plane, 128B / 8B unit)
  const int so_plane = tid >> 8;
  const int so_i = tid & 255;
  const size_t slab = (size_t)rg * 32768;

  // zero own h'-region of parity 0
  sta8(ws + HP + (size_t)so_plane * HPLANE + slab + (size_t)cb * 2048 +
           (size_t)so_i * 8,
       0ull);

  float hold[4] = {0.f, 0.f, 0.f, 0.f};
  const float fcb_s = *fcb;
  const float fcw_l = fcW[jc];

  bt += 16;
  gbar(bar, bt);

  for (int phase = 0; phase < 2; ++phase) {
    // register-resident W_hh B-frags for (jg, kh): [gate][kk]
    half8 bW[48];
    {
      const char* wf = ws + (phase ? WF_D : WF_E);
#pragma unroll
      for (int g = 0; g < 3; ++g)
#pragma unroll
        for (int kk = 0; kk < 16; ++kk)
          bW[g * 16 + kk] = *(const half8*)(
              wf + (size_t)((g * 64 + jg) * 32 + kh * 16 + kk) * 1024 +
              (size_t)L * 16);
    }
    const float* bih = phase ? bih_d : bih_e;
    const float* bhh = phase ? bhh_d : bhh_e;
    const float b_r  = bih[jc]          + bhh[jc];
    const float b_z  = bih[H_ + jc]     + bhh[H_ + jc];
    const float b_in = bih[2 * H_ + jc];
    const float b_hn = bhh[2 * H_ + jc];
    float wd_r = 0.f, wd_z = 0.f, wd_n = 0.f;
    if (phase) {
      wd_r = Wih_d[jc]; wd_z = Wih_d[H_ + jc]; wd_n = Wih_d[2 * H_ + jc];
    }

    const int nsteps = phase ? TL_ : T_;
    for (int d = 0; d < nsteps; ++d) {
      const int s = phase ? T_ + d : d;

      // ---- decoder scalar input from previous step's fc partials ----
      if (phase && tid < 16) {
        float sum = 0.f;
        if (d > 0) {
          const float* pb =
              (const float*)(ws + PB) + (size_t)((d + 1) & 1) * 64 * 256;
          int row = rg * 16 + tid;
          float a = fcb_s;
          for (int jj = 0; jj < 64; ++jj) a += lda4f(&pb[jj * 256 + row]);
          sum = a;
          if (cb == 0) out[(size_t)row * TL_ + (d - 1)] = a;
        }
        inp_lds[tid] = sum;
      }

      // ---- stage A slab (hi+lo, 64KB) into LDS: 128B/thread, 16B
      //      sc0sc1 loads, xor-swizzled ds_writes ----
      {
        const char* src = ws + HP + (size_t)(s & 1) * (2 * HPLANE) +
                          (size_t)so_plane * HPLANE + slab +
                          (size_t)so_i * 128;
        floatx4 t0, t1, t2, t3, t4, t5, t6, t7;
        asm volatile(
            "global_load_dwordx4 %0, %8, off sc0 sc1\n\t"
            "global_load_dwordx4 %1, %8, off offset:16 sc0 sc1\n\t"
            "global_load_dwordx4 %2, %8, off offset:32 sc0 sc1\n\t"
            "global_load_dwordx4 %3, %8, off offset:48 sc0 sc1\n\t"
            "global_load_dwordx4 %4, %8, off offset:64 sc0 sc1\n\t"
            "global_load_dwordx4 %5, %8, off offset:80 sc0 sc1\n\t"
            "global_load_dwordx4 %6, %8, off offset:96 sc0 sc1\n\t"
            "global_load_dwordx4 %7, %8, off offset:112 sc0 sc1\n\t"
            "s_waitcnt vmcnt(0)"
            : "=&v"(t0), "=&v"(t1), "=&v"(t2), "=&v"(t3), "=&v"(t4),
              "=&v"(t5), "=&v"(t6), "=&v"(t7)
            : "v"(src)
            : "memory");
        char* wb = atile + so_plane * 32768 + so_i * 128;
        const int csw = (so_i & 7) << 4;
        *(floatx4*)(wb + ((0 << 4) ^ csw)) = t0;
        *(floatx4*)(wb + ((1 << 4) ^ csw)) = t1;
        *(floatx4*)(wb + ((2 << 4) ^ csw)) = t2;
        *(floatx4*)(wb + ((3 << 4) ^ csw)) = t3;
        *(floatx4*)(wb + ((4 << 4) ^ csw)) = t4;
        *(floatx4*)(wb + ((5 << 4) ^ csw)) = t5;
        *(floatx4*)(wb + ((6 << 4) ^ csw)) = t6;
        *(floatx4*)(wb + ((7 << 4) ^ csw)) = t7;
      }
      __syncthreads();

      floatx4 a0 = {0.f, 0.f, 0.f, 0.f}, a1 = {0.f, 0.f, 0.f, 0.f};
      floatx4 a2 = {0.f, 0.f, 0.f, 0.f}, aI = {0.f, 0.f, 0.f, 0.f};

      // ---- h-GEMM, this wave's K-half, hi+lo planes ----
#pragma unroll
      for (int kk = 0; kk < 16; ++kk) {
        const int kb = kh * 16 + kk;
        half8 ahi = *(const half8*)(atile + kb * 1024 + lswz);
        half8 alo = *(const half8*)(atile + 32768 + kb * 1024 + lswz);
        a0 = MFMA(ahi, bW[kk], a0);
        a0 = MFMA(alo, bW[kk], a0);
        a1 = MFMA(ahi, bW[16 + kk], a1);
        a1 = MFMA(alo, bW[16 + kk], a1);
        a2 = MFMA(ahi, bW[32 + kk], a2);
        a2 = MFMA(alo, bW[32 + kk], a2);
      }

      // ---- kh1: encoder x-projection + dump partials ----
      if (kh == 1) {
        if (!phase) {
          const float* xp =
              x + ((size_t)(rg * 16 + r) * T_ + s) * F_ + q * 8;
#pragma unroll
          for (int kc = 0; kc < 2; ++kc) {
            floatx4 x0 = *(const floatx4*)(xp + kc * 32);
            floatx4 x1 = *(const floatx4*)(xp + kc * 32 + 4);
            half8 xa;
#pragma unroll
            for (int i = 0; i < 4; ++i) {
              xa[i] = (_Float16)x0[i];
              xa[4 + i] = (_Float16)x1[i];
            }
            // bWI reloaded via cached loads (L1-hot) to save 24 VGPRs
            const char* wfi = ws + WF_I;
            a0 = MFMA(xa, *(const half8*)(wfi +
                     (size_t)((0 * 64 + jg) * 2 + kc) * 1024 + (size_t)L * 16), a0);
            a1 = MFMA(xa, *(const half8*)(wfi +
                     (size_t)((1 * 64 + jg) * 2 + kc) * 1024 + (size_t)L * 16), a1);
            aI = MFMA(xa, *(const half8*)(wfi +
                     (size_t)((2 * 64 + jg) * 2 + kc) * 1024 + (size_t)L * 16), aI);
          }
        }
        float* rd = &red[(jp * 64 + L) * 17];
#pragma unroll
        for (int i = 0; i < 4; ++i) {
          rd[i] = a0[i];
          rd[4 + i] = a1[i];
          rd[8 + i] = a2[i];
        }
        if (!phase) {
#pragma unroll
          for (int i = 0; i < 4; ++i) rd[12 + i] = aI[i];
        }
      }
      __syncthreads();

      // ---- kh0: reduce halves, gate epilogue, h' -> otile ----
      if (kh == 0) {
        const float* rd = &red[(jp * 64 + L) * 17];
        const size_t tbase = (size_t)(jp >> 1) * 1024 +
                             (size_t)((jp & 1) * 2 + (r >> 3)) * 256 +
                             (size_t)(r & 7) * 2;
        float pv[4];
#pragma unroll
        for (int i = 0; i < 4; ++i) {
          float rpre = a0[i] + rd[i] + b_r;
          float zpre = a1[i] + rd[4 + i] + b_z;
          float hn   = a2[i] + rd[8 + i] + b_hn;
          float inn  = b_in + (phase ? 0.f : rd[12 + i]);
          if (phase) {
            float inp = inp_lds[q * 4 + i];
            rpre += inp * wd_r;
            zpre += inp * wd_z;
            inn  += inp * wd_n;
          }
          float rg_ = 1.f / (1.f + __expf(-rpre));
          float zg = 1.f / (1.f + __expf(-zpre));
          float t2 = __expf(-2.f * (inn + rg_ * hn));
          float ng = 2.f / (1.f + t2) - 1.f;  // tanh, safe at +-inf
          float hnew = (1.f - zg) * ng + zg * hold[i];
          hold[i] = hnew;
          _Float16 hhi = (_Float16)hnew;
          float lo = hnew - (float)hhi;
          _Float16 hlo = (_Float16)lo;
          size_t to = tbase + (size_t)(q * 4 + i) * 16;
          *(_Float16*)(otile + to) = hhi;
          *(_Float16*)(otile + 2048 + to) = hlo;
          pv[i] = hnew * fcw_l;
        }
        if (phase) {
#pragma unroll
          for (int i = 0; i < 4; ++i) {
            float v = pv[i];
            v += __shfl_xor(v, 1);
            v += __shfl_xor(v, 2);
            v += __shfl_xor(v, 4);
            v += __shfl_xor(v, 8);
            if (r == 0) {
              float* pb = (float*)(ws + PB) + (size_t)(d & 1) * 64 * 256;
              __hip_atomic_store(&pb[jg * 256 + (rg * 16 + q * 4 + i)], v,
                                 __ATOMIC_RELAXED, __HIP_MEMORY_SCOPE_AGENT);
            }
          }
        }
      }
      __syncthreads();

      // ---- stream h' (4KB) out: coalesced 8B LLC stores ----
      {
        ull v = *(const ull*)(otile + (size_t)tid * 8);
        sta8(ws + HP + (size_t)((s + 1) & 1) * (2 * HPLANE) +
                 (size_t)so_plane * HPLANE + slab + (size_t)cb * 2048 +
                 (size_t)so_i * 8,
             v);
      }

      bt += 16;
      gbar(bar, bt);
    }
  }

  // ---- final output column t = TL-1 ----
  if (cb == 0 && tid < 16) {
    const float* pb =
        (const float*)(ws + PB) + (size_t)((TL_ - 1) & 1) * 64 * 256;
    int row = rg * 16 + tid;
    float a = fcb_s;
    for (int jj = 0; jj < 64; ++jj) a += lda4f(&pb[jj * 256 + row]);
    out[(size_t)row * TL_ + (TL_ - 1)] = a;
  }
}

// ---------------------------------------------------------------------------
extern "C" void kernel_launch(void* const* d_in, const int* in_sizes, int n_in,
                              void* d_out, int out_size, void* d_ws,
                              size_t ws_size, hipStream_t stream) {
  const float* x     = (const float*)d_in[0];
  const float* WihE  = (const float*)d_in[1];
  const float* WhhE  = (const float*)d_in[2];
  const float* bihE  = (const float*)d_in[3];
  const float* bhhE  = (const float*)d_in[4];
  const float* WihD  = (const float*)d_in[5];
  const float* WhhD  = (const float*)d_in[6];
  const float* bihD  = (const float*)d_in[7];
  const float* bhhD  = (const float*)d_in[8];
  const float* fcW   = (const float*)d_in[9];
  const float* fcb   = (const float*)d_in[10];
  float* outp = (float*)d_out;
  char* ws = (char*)d_ws;

  gru_setup<<<3168, 256, 0, stream>>>(WhhE, WhhD, WihE, ws);

  gru_main<<<dim3(256), dim3(512), 0, stream>>>(
      x, bihE, bhhE, WihD, bihD, bhhD, fcW, fcb, outp, ws);
}

// Round 6
// 4659.764 us; speedup vs baseline: 5.3759x; 1.1233x over previous
//
#include <hip/hip_runtime.h>

#define B_  256
#define T_  512
#define F_  64
#define H_  1024
#define TL_ 64

typedef _Float16 half8 __attribute__((ext_vector_type(8)));
typedef float   floatx4 __attribute__((ext_vector_type(4)));
typedef unsigned long long ull;

#define MFMA(a, b, c) __builtin_amdgcn_mfma_f32_16x16x32_f16(a, b, c, 0, 0, 0)

// ws layout (bytes)
#define WF_E   0UL          // W_hh enc fragments: 3*64*32 chunks * 1024B
#define WF_D   6291456UL    // W_hh dec fragments
#define WF_I   12582912UL   // W_ih enc fragments: 3*64*2 chunks * 1024B
#define HP     12976128UL   // h planes: [2 parity][hi,lo]; plane = 512KB
#define PB     15073280UL   // fc partials: [2][64 jg][256 rows] f32
#define BARS   15204352UL   // 16 group counters, 128B apart
#define HPLANE 524288UL
// h plane layout (fragment-major): [rg 16][kb 32][lane 64][16B]; slab for
// row-group rg = 32KB/plane; block (rg,cb) owns the contiguous 2KB at
// rg*32768 + cb*2048.

// LLC-coherent scalar atomics (sc0 sc1: bypass L1/L2, coherent at IF).
__device__ __forceinline__ void sta8(void* p, ull v) {
  __hip_atomic_store((ull*)p, v, __ATOMIC_RELAXED, __HIP_MEMORY_SCOPE_AGENT);
}
__device__ __forceinline__ float lda4f(const float* p) {
  return __hip_atomic_load(p, __ATOMIC_RELAXED, __HIP_MEMORY_SCOPE_AGENT);
}

// ---------------------------------------------------------------------------
// Setup: W_hh (enc,dec) and W_ih (enc) fp32 -> fp16 MFMA-B fragment layout.
// B-frag 16x16x32: lane L holds B[k=(L>>4)*8+t][n=L&15] ->
// W[g*H + jg*16 + (L&15)][kb*32 + (L>>4)*8 + t].
// Chunk c = (((g*64+jg)*32 + kb)*4 + q)*16 + r ; 16B per chunk-lane.
// ---------------------------------------------------------------------------
__global__ void gru_setup(const float* __restrict__ WhhE,
                          const float* __restrict__ WhhD,
                          const float* __restrict__ WihE,
                          char* __restrict__ ws) {
  int t = blockIdx.x * 256 + threadIdx.x;
  if (t < 512) ((unsigned int*)(ws + BARS))[t] = 0u;
  const int NW = 3 * 64 * 32 * 4 * 16;
  if (t < 2 * NW) {
    const float* W = (t < NW) ? WhhE : WhhD;
    size_t dst = (t < NW) ? WF_E : WF_D;
    int c = (t < NW) ? t : t - NW;
    int r = c & 15, q = (c >> 4) & 3, kb = (c >> 6) & 31, gj = c >> 11;
    int row = (gj >> 6) * H_ + (gj & 63) * 16 + r;
    const float* src = W + (size_t)row * H_ + kb * 32 + q * 8;
    half8 v;
#pragma unroll
    for (int i = 0; i < 8; ++i) v[i] = (_Float16)src[i];
    *(half8*)(ws + dst + (size_t)c * 16) = v;
  } else if (t < 2 * NW + 3 * 64 * 2 * 4 * 16) {
    int c = t - 2 * NW;
    int r = c & 15, q = (c >> 4) & 3, kc = (c >> 6) & 1, gj = c >> 7;
    int row = (gj >> 6) * H_ + (gj & 63) * 16 + r;
    const float* src = WihE + (size_t)row * F_ + kc * 32 + q * 8;
    half8 v;
#pragma unroll
    for (int i = 0; i < 8; ++i) v[i] = (_Float16)src[i];
    *(half8*)(ws + WF_I + (size_t)c * 16) = v;
  }
}

// Group barrier: 16 blocks (same rg), own cacheline, relaxed LLC atomics.
__device__ __forceinline__ void gbar(unsigned int* cnt, unsigned int target) {
  __syncthreads();
  if (threadIdx.x == 0) {
    __hip_atomic_fetch_add(cnt, 1u, __ATOMIC_RELAXED,
                           __HIP_MEMORY_SCOPE_AGENT);
    while (__hip_atomic_load(cnt, __ATOMIC_RELAXED,
                             __HIP_MEMORY_SCOPE_AGENT) < target)
      __builtin_amdgcn_s_sleep(1);
  }
  __syncthreads();
}

// ---------------------------------------------------------------------------
// Main persistent kernel: 256 blocks x 512 thr (8 waves, 1 block/CU).
// Block (rg = bx&15, cb = bx>>4): rows [rg*16,+16), h-cols [cb*64,+64).
// Wave w: jp = w&3 (jg = cb*4+jp), kh = w>>2 (K-half). B-frags: 48 chunks =
// 192 VGPR/wave, pinned via asm register-opacity (round-5 compiler chose
// 128 VGPRs and re-loaded 384KB/block/step from L2 = the dominant term).
// A slab staged to LDS via global_load_lds_dwordx4 sc0sc1 (no VGPR temps,
// no ds_write bank conflicts). kh halves exchange partials via LDS.
// ---------------------------------------------------------------------------
__global__ __launch_bounds__(512, 2) void gru_main(
    const float* __restrict__ x,
    const float* __restrict__ bih_e, const float* __restrict__ bhh_e,
    const float* __restrict__ Wih_d,
    const float* __restrict__ bih_d, const float* __restrict__ bhh_d,
    const float* __restrict__ fcW, const float* __restrict__ fcb,
    float* __restrict__ out, char* __restrict__ ws) {

  __shared__ __align__(128) char atile[65536];  // [plane 2][kb 32][L 64][16B]
  __shared__ float red[4 * 64 * 17];            // kh1 partials [jp][L][17]
  __shared__ __align__(16) char otile[4096];    // h' image [plane 2][2KB]
  __shared__ float inp_lds[16];

  const int tid = threadIdx.x;
  const int L = tid & 63;
  const int w = tid >> 6;
  const int jp = w & 3;
  const int kh = w >> 2;
  const int bx = blockIdx.x;
  const int rg = bx & 15;
  const int cb = bx >> 4;
  const int r = L & 15;
  const int q = L >> 4;
  const int jg = cb * 4 + jp;
  const int jc = jg * 16 + r;

  unsigned int* bar = (unsigned int*)(ws + BARS) + (size_t)rg * 32;
  unsigned int bt = 0;

  // stream-out mapping: thread -> (plane, 8B unit) of the block's own 2KB
  const int so_plane = tid >> 8;
  const int so_i = tid & 255;
  const size_t slab = (size_t)rg * 32768;

  // zero own h'-region of parity 0
  sta8(ws + HP + (size_t)so_plane * HPLANE + slab + (size_t)cb * 2048 +
           (size_t)so_i * 8,
       0ull);

  float hold[4] = {0.f, 0.f, 0.f, 0.f};
  const float fcb_s = *fcb;
  const float fcw_l = fcW[jc];

  bt += 16;
  gbar(bar, bt);

  for (int phase = 0; phase < 2; ++phase) {
    // register-resident W_hh B-frags for (jg, kh): [gate][kk].
    half8 bW[48];
    {
      const char* wf = ws + (phase ? WF_D : WF_E);
#pragma unroll
      for (int g = 0; g < 3; ++g)
#pragma unroll
        for (int kk = 0; kk < 16; ++kk)
          bW[g * 16 + kk] = *(const half8*)(
              wf + (size_t)((g * 64 + jg) * 32 + kh * 16 + kk) * 1024 +
              (size_t)L * 16);
      // Opacity pin: values can no longer be rematerialized by re-loading,
      // so the allocator must keep all 192 VGPRs live across the step loop.
#pragma unroll
      for (int i = 0; i < 48; ++i) asm volatile("" : "+v"(bW[i]));
    }
    const float* bih = phase ? bih_d : bih_e;
    const float* bhh = phase ? bhh_d : bhh_e;
    const float b_r  = bih[jc]          + bhh[jc];
    const float b_z  = bih[H_ + jc]     + bhh[H_ + jc];
    const float b_in = bih[2 * H_ + jc];
    const float b_hn = bhh[2 * H_ + jc];
    float wd_r = 0.f, wd_z = 0.f, wd_n = 0.f;
    if (phase) {
      wd_r = Wih_d[jc]; wd_z = Wih_d[H_ + jc]; wd_n = Wih_d[2 * H_ + jc];
    }

    const int nsteps = phase ? TL_ : T_;
    for (int d = 0; d < nsteps; ++d) {
      const int s = phase ? T_ + d : d;

      // ---- stage A slab (hi+lo, 64KB) via async global->LDS DMA,
      //      LLC-coherent (aux 17 = sc0|sc1). Wave w stages segments
      //      w*8..w*8+7; lane L's 16B lands at seg base + L*16. ----
      {
        const char* srcbase = ws + HP + (size_t)(s & 1) * (2 * HPLANE) + slab;
#pragma unroll
        for (int c = 0; c < 8; ++c) {
          const int seg = w * 8 + c;       // 0..63
          const int plane = seg >> 5;      // hi / lo
          const int kb = seg & 31;
          const char* src = srcbase + (size_t)plane * HPLANE +
                            (size_t)kb * 1024 + (size_t)L * 16;
          __builtin_amdgcn_global_load_lds(
              (const __attribute__((address_space(1))) void*)src,
              (__attribute__((address_space(3))) void*)(atile + seg * 1024),
              16, 0, 17);
        }
      }

      // ---- decoder scalar input (overlaps the staging DMA) ----
      if (phase && tid < 16) {
        float sum = 0.f;
        if (d > 0) {
          const float* pb =
              (const float*)(ws + PB) + (size_t)((d + 1) & 1) * 64 * 256;
          int row = rg * 16 + tid;
          float a = fcb_s;
          for (int jj = 0; jj < 64; ++jj) a += lda4f(&pb[jj * 256 + row]);
          sum = a;
          if (cb == 0) out[(size_t)row * TL_ + (d - 1)] = a;
        }
        inp_lds[tid] = sum;
      }
      __syncthreads();  // drains vmcnt -> DMA complete

      floatx4 a0 = {0.f, 0.f, 0.f, 0.f}, a1 = {0.f, 0.f, 0.f, 0.f};
      floatx4 a2 = {0.f, 0.f, 0.f, 0.f}, aI = {0.f, 0.f, 0.f, 0.f};

      // ---- h-GEMM, this wave's K-half, hi+lo planes (stride-1 ds_read) ----
#pragma unroll
      for (int kk = 0; kk < 16; ++kk) {
        const int kb = kh * 16 + kk;
        half8 ahi = *(const half8*)(atile + kb * 1024 + L * 16);
        half8 alo = *(const half8*)(atile + 32768 + kb * 1024 + L * 16);
        a0 = MFMA(ahi, bW[kk], a0);
        a0 = MFMA(alo, bW[kk], a0);
        a1 = MFMA(ahi, bW[16 + kk], a1);
        a1 = MFMA(alo, bW[16 + kk], a1);
        a2 = MFMA(ahi, bW[32 + kk], a2);
        a2 = MFMA(alo, bW[32 + kk], a2);
      }

      // ---- kh1: encoder x-projection + dump partials ----
      if (kh == 1) {
        if (!phase) {
          const float* xp =
              x + ((size_t)(rg * 16 + r) * T_ + s) * F_ + q * 8;
#pragma unroll
          for (int kc = 0; kc < 2; ++kc) {
            floatx4 x0 = *(const floatx4*)(xp + kc * 32);
            floatx4 x1 = *(const floatx4*)(xp + kc * 32 + 4);
            half8 xa;
#pragma unroll
            for (int i = 0; i < 4; ++i) {
              xa[i] = (_Float16)x0[i];
              xa[4 + i] = (_Float16)x1[i];
            }
            const char* wfi = ws + WF_I;  // L1-hot reloads, saves 24 VGPRs
            a0 = MFMA(xa, *(const half8*)(wfi +
                     (size_t)((0 * 64 + jg) * 2 + kc) * 1024 + (size_t)L * 16), a0);
            a1 = MFMA(xa, *(const half8*)(wfi +
                     (size_t)((1 * 64 + jg) * 2 + kc) * 1024 + (size_t)L * 16), a1);
            aI = MFMA(xa, *(const half8*)(wfi +
                     (size_t)((2 * 64 + jg) * 2 + kc) * 1024 + (size_t)L * 16), aI);
          }
        }
        float* rd = &red[(jp * 64 + L) * 17];
#pragma unroll
        for (int i = 0; i < 4; ++i) {
          rd[i] = a0[i];
          rd[4 + i] = a1[i];
          rd[8 + i] = a2[i];
        }
        if (!phase) {
#pragma unroll
          for (int i = 0; i < 4; ++i) rd[12 + i] = aI[i];
        }
      }
      __syncthreads();

      // ---- kh0: reduce halves, gate epilogue, h' -> otile ----
      if (kh == 0) {
        const float* rd = &red[(jp * 64 + L) * 17];
        const size_t tbase = (size_t)(jp >> 1) * 1024 +
                             (size_t)((jp & 1) * 2 + (r >> 3)) * 256 +
                             (size_t)(r & 7) * 2;
        float pv[4];
#pragma unroll
        for (int i = 0; i < 4; ++i) {
          float rpre = a0[i] + rd[i] + b_r;
          float zpre = a1[i] + rd[4 + i] + b_z;
          float hn   = a2[i] + rd[8 + i] + b_hn;
          float inn  = b_in + (phase ? 0.f : rd[12 + i]);
          if (phase) {
            float inp = inp_lds[q * 4 + i];
            rpre += inp * wd_r;
            zpre += inp * wd_z;
            inn  += inp * wd_n;
          }
          float rg_ = 1.f / (1.f + __expf(-rpre));
          float zg = 1.f / (1.f + __expf(-zpre));
          float t2 = __expf(-2.f * (inn + rg_ * hn));
          float ng = 2.f / (1.f + t2) - 1.f;  // tanh, safe at +-inf
          float hnew = (1.f - zg) * ng + zg * hold[i];
          hold[i] = hnew;
          _Float16 hhi = (_Float16)hnew;
          float lo = hnew - (float)hhi;
          _Float16 hlo = (_Float16)lo;
          size_t to = tbase + (size_t)(q * 4 + i) * 16;
          *(_Float16*)(otile + to) = hhi;
          *(_Float16*)(otile + 2048 + to) = hlo;
          pv[i] = hnew * fcw_l;
        }
        if (phase) {
#pragma unroll
          for (int i = 0; i < 4; ++i) {
            float v = pv[i];
            v += __shfl_xor(v, 1);
            v += __shfl_xor(v, 2);
            v += __shfl_xor(v, 4);
            v += __shfl_xor(v, 8);
            if (r == 0) {
              float* pb = (float*)(ws + PB) + (size_t)(d & 1) * 64 * 256;
              __hip_atomic_store(&pb[jg * 256 + (rg * 16 + q * 4 + i)], v,
                                 __ATOMIC_RELAXED, __HIP_MEMORY_SCOPE_AGENT);
            }
          }
        }
      }
      __syncthreads();

      // ---- stream h' (4KB) out: coalesced 8B LLC stores ----
      {
        ull v = *(const ull*)(otile + (size_t)tid * 8);
        sta8(ws + HP + (size_t)((s + 1) & 1) * (2 * HPLANE) +
                 (size_t)so_plane * HPLANE + slab + (size_t)cb * 2048 +
                 (size_t)so_i * 8,
             v);
      }

      bt += 16;
      gbar(bar, bt);
    }
  }

  // ---- final output column t = TL-1 ----
  if (cb == 0 && tid < 16) {
    const float* pb =
        (const float*)(ws + PB) + (size_t)((TL_ - 1) & 1) * 64 * 256;
    int row = rg * 16 + tid;
    float a = fcb_s;
    for (int jj = 0; jj < 64; ++jj) a += lda4f(&pb[jj * 256 + row]);
    out[(size_t)row * TL_ + (TL_ - 1)] = a;
  }
}

// ---------------------------------------------------------------------------
extern "C" void kernel_launch(void* const* d_in, const int* in_sizes, int n_in,
                              void* d_out, int out_size, void* d_ws,
                              size_t ws_size, hipStream_t stream) {
  const float* x     = (const float*)d_in[0];
  const float* WihE  = (const float*)d_in[1];
  const float* WhhE  = (const float*)d_in[2];
  const float* bihE  = (const float*)d_in[3];
  const float* bhhE  = (const float*)d_in[4];
  const float* WihD  = (const float*)d_in[5];
  const float* WhhD  = (const float*)d_in[6];
  const float* bihD  = (const float*)d_in[7];
  const float* bhhD  = (const float*)d_in[8];
  const float* fcW   = (const float*)d_in[9];
  const float* fcb   = (const float*)d_in[10];
  float* outp = (float*)d_out;
  char* ws = (char*)d_ws;

  gru_setup<<<3168, 256, 0, stream>>>(WhhE, WhhD, WihE, ws);

  gru_main<<<dim3(256), dim3(512), 0, stream>>>(
      x, bihE, bhhE, WihD, bihD, bhhD, fcW, fcb, outp, ws);
}